// Round 1
// baseline (587.867 us; speedup 1.0000x reference)
//
#include <hip/hip_runtime.h>

// bf16 helpers ---------------------------------------------------------------
using short8  = __attribute__((ext_vector_type(8))) short;
using floatx4 = __attribute__((ext_vector_type(4))) float;

__device__ __forceinline__ unsigned short f2bf(float f) {
    unsigned u = __float_as_uint(f);
    u += 0x7fff + ((u >> 16) & 1);   // round-to-nearest-even
    return (unsigned short)(u >> 16);
}
__device__ __forceinline__ float bf2f(unsigned short h) {
    return __uint_as_float(((unsigned)h) << 16);
}

// 1) convert x f32 -> bf16 ----------------------------------------------------
__global__ __launch_bounds__(256) void cvt_f32_bf16_kernel(
        const float* __restrict__ in, unsigned short* __restrict__ out) {
    long i = ((long)blockIdx.x * 256 + threadIdx.x) * 4;
    float4 v = *(const float4*)(in + i);
    ushort4 o;
    o.x = f2bf(v.x); o.y = f2bf(v.y); o.z = f2bf(v.z); o.w = f2bf(v.w);
    *(ushort4*)(out + i) = o;
}

// 2) W [1024][1024] f32 -> Wt bf16 [e][d] (transpose+convert), 3 weights ------
__global__ __launch_bounds__(256) void wt_kernel(
        const float* __restrict__ W0, const float* __restrict__ W1, const float* __restrict__ W2,
        unsigned short* __restrict__ O0, unsigned short* __restrict__ O1, unsigned short* __restrict__ O2) {
    const float* W = blockIdx.z == 0 ? W0 : blockIdx.z == 1 ? W1 : W2;
    unsigned short* O = blockIdx.z == 0 ? O0 : blockIdx.z == 1 ? O1 : O2;
    __shared__ float t[32][33];
    const int cx = threadIdx.x & 31, ry = threadIdx.x >> 5;
    const int d0 = blockIdx.x * 32, e0 = blockIdx.y * 32;
#pragma unroll
    for (int i = 0; i < 4; i++) t[ry + i * 8][cx] = W[(long)(d0 + ry + i * 8) * 1024 + e0 + cx];
    __syncthreads();
#pragma unroll
    for (int i = 0; i < 4; i++) O[(long)(e0 + ry + i * 8) * 1024 + d0 + cx] = f2bf(t[cx][ry + i * 8]);
}

// 3) V bf16 [4][2048][1024] -> Vt bf16 [4][1024][2048] ------------------------
__global__ __launch_bounds__(256) void vt_kernel(
        const unsigned short* __restrict__ V, unsigned short* __restrict__ Vt) {
    const int b = blockIdx.z;
    const unsigned short* v = V + (long)b * 2048 * 1024;
    unsigned short* o = Vt + (long)b * 1024 * 2048;
    __shared__ unsigned short t[32][33];
    const int cx = threadIdx.x & 31, ry = threadIdx.x >> 5;
    const int e0 = blockIdx.x * 32, t0 = blockIdx.y * 32;
#pragma unroll
    for (int i = 0; i < 4; i++) t[ry + i * 8][cx] = v[(long)(t0 + ry + i * 8) * 1024 + e0 + cx];
    __syncthreads();
#pragma unroll
    for (int i = 0; i < 4; i++) o[(long)(e0 + ry + i * 8) * 2048 + t0 + cx] = t[cx][ry + i * 8];
}

// 4) GEMM: C[M][N] = A[M][K] @ Bt[N][K]^T (+bias) (*scale); bf16 in, bf16/f32 out
//    128x128 tile, 4 waves (2x2), each wave 64x64 = 4x4 frags of 16x16x32 MFMA.
template <bool HAS_BIAS, bool OUT_BF16, bool SCALE>
__global__ __launch_bounds__(256) void gemm_kernel(
        const unsigned short* __restrict__ A, const unsigned short* __restrict__ Bt,
        const float* __restrict__ bias, void* __restrict__ Cout,
        int M, int N, int K, long sAb, long sBb, long sCb, float scale) {
    __shared__ __align__(16) unsigned short sA[128][72];  // +8 pad: kills bank conflicts
    __shared__ __align__(16) unsigned short sB[128][72];
    const int tid  = threadIdx.x;
    const int lane = tid & 63;
    const int wave = tid >> 6;
    const int wm = wave >> 1, wn = wave & 1;
    const long m0 = (long)blockIdx.y * 128, n0 = (long)blockIdx.x * 128;
    A  += (long)blockIdx.z * sAb;
    Bt += (long)blockIdx.z * sBb;

    floatx4 acc[4][4] = {};

    const int sr = tid >> 3;        // staging row 0..31
    const int sc = (tid & 7) * 8;   // staging col (bf16 units)

    for (int k0 = 0; k0 < K; k0 += 64) {
        int4 av[4], bv[4];
#pragma unroll
        for (int i = 0; i < 4; i++) {
            av[i] = *(const int4*)(A  + (m0 + sr + i * 32) * (long)K + k0 + sc);
            bv[i] = *(const int4*)(Bt + (n0 + sr + i * 32) * (long)K + k0 + sc);
        }
        __syncthreads();            // prior compute done reading LDS
#pragma unroll
        for (int i = 0; i < 4; i++) {
            *(int4*)&sA[sr + i * 32][sc] = av[i];
            *(int4*)&sB[sr + i * 32][sc] = bv[i];
        }
        __syncthreads();            // tile staged
#pragma unroll
        for (int ks = 0; ks < 2; ks++) {
            short8 af[4], bfr[4];
#pragma unroll
            for (int f = 0; f < 4; f++) {
                af[f]  = *(const short8*)&sA[wm * 64 + f * 16 + (lane & 15)][ks * 32 + (lane >> 4) * 8];
                bfr[f] = *(const short8*)&sB[wn * 64 + f * 16 + (lane & 15)][ks * 32 + (lane >> 4) * 8];
            }
#pragma unroll
            for (int fm = 0; fm < 4; fm++)
#pragma unroll
                for (int fn = 0; fn < 4; fn++)
                    acc[fm][fn] = __builtin_amdgcn_mfma_f32_16x16x32_bf16(af[fm], bfr[fn], acc[fm][fn], 0, 0, 0);
        }
    }
    // epilogue: C/D layout col=lane&15, row=(lane>>4)*4+j (HW-verified)
    const int cr = (lane >> 4) * 4, cc = lane & 15;
#pragma unroll
    for (int fn = 0; fn < 4; fn++) {
        const long col = n0 + wn * 64 + fn * 16 + cc;
        float bvv = HAS_BIAS ? bias[col] : 0.f;
#pragma unroll
        for (int fm = 0; fm < 4; fm++) {
            const long rbase = m0 + wm * 64 + fm * 16 + cr;
#pragma unroll
            for (int j = 0; j < 4; j++) {
                float v = acc[fm][fn][j];
                if (SCALE) v *= scale;
                v += bvv;
                const long idx = (long)blockIdx.z * sCb + (rbase + j) * (long)N + col;
                if (OUT_BF16) ((unsigned short*)Cout)[idx] = f2bf(v);
                else          ((float*)Cout)[idx] = v;
            }
        }
    }
}

// 5) in-place row softmax over 2048 bf16 --------------------------------------
__global__ __launch_bounds__(256) void softmax_kernel(unsigned short* __restrict__ S) {
    unsigned short* p = S + (long)blockIdx.x * 2048;
    const int tid = threadIdx.x;
    union { int4 q; unsigned short u[8]; } in;
    in.q = *(const int4*)(p + tid * 8);
    float v[8];
#pragma unroll
    for (int i = 0; i < 8; i++) v[i] = bf2f(in.u[i]);
    float mx = v[0];
#pragma unroll
    for (int i = 1; i < 8; i++) mx = fmaxf(mx, v[i]);
#pragma unroll
    for (int off = 32; off; off >>= 1) mx = fmaxf(mx, __shfl_xor(mx, off));
    __shared__ float red[8];
    if ((tid & 63) == 0) red[tid >> 6] = mx;
    __syncthreads();
    mx = fmaxf(fmaxf(red[0], red[1]), fmaxf(red[2], red[3]));
    float s = 0.f;
#pragma unroll
    for (int i = 0; i < 8; i++) { v[i] = __expf(v[i] - mx); s += v[i]; }
#pragma unroll
    for (int off = 32; off; off >>= 1) s += __shfl_xor(s, off);
    if ((tid & 63) == 0) red[4 + (tid >> 6)] = s;
    __syncthreads();
    s = red[4] + red[5] + red[6] + red[7];
    const float inv = 1.f / s;
    union { int4 q; unsigned short u[8]; } out;
#pragma unroll
    for (int i = 0; i < 8; i++) out.u[i] = f2bf(v[i] * inv);
    *(int4*)(p + tid * 8) = out.q;
}

// -----------------------------------------------------------------------------
extern "C" void kernel_launch(void* const* d_in, const int* in_sizes, int n_in,
                              void* d_out, int out_size, void* d_ws, size_t ws_size,
                              hipStream_t stream) {
    const float* x  = (const float*)d_in[0];
    const float* Wq = (const float*)d_in[1];
    const float* bq = (const float*)d_in[2];
    const float* Wk = (const float*)d_in[3];
    const float* bk = (const float*)d_in[4];
    const float* Wv = (const float*)d_in[5];
    const float* bv = (const float*)d_in[6];
    float* out = (float*)d_out;

    char* ws = (char*)d_ws;
    const long MB = 1L << 20;
    unsigned short* xb  = (unsigned short*)(ws);            // 16 MB  x bf16 [8192][1024]
    unsigned short* wtq = (unsigned short*)(ws + 16 * MB);  // 2 MB   Wq^T bf16 [e][d]
    unsigned short* wtk = (unsigned short*)(ws + 18 * MB);
    unsigned short* wtv = (unsigned short*)(ws + 20 * MB);
    unsigned short* Q   = (unsigned short*)(ws + 22 * MB);  // 16 MB  [4][2048][1024]
    unsigned short* Kb  = (unsigned short*)(ws + 38 * MB);  // 16 MB
    unsigned short* Vb  = (unsigned short*)(ws + 54 * MB);  // 16 MB
    unsigned short* Vt  = (unsigned short*)(ws + 70 * MB);  // 16 MB  [4][1024][2048]
    unsigned short* Sc  = (unsigned short*)(ws + 86 * MB);  // 32 MB  scores/attn [4][2048][2048]

    // x -> bf16
    cvt_f32_bf16_kernel<<<8192, 256, 0, stream>>>(x, xb);
    // W -> Wt bf16 (transposed)
    wt_kernel<<<dim3(32, 32, 3), 256, 0, stream>>>(Wq, Wk, Wv, wtq, wtk, wtv);
    // Q/K/V = x @ W + b   (M=8192, N=1024, K=1024)
    gemm_kernel<true, true, false><<<dim3(8, 64, 1), 256, 0, stream>>>(xb, wtq, bq, Q,  8192, 1024, 1024, 0, 0, 0, 1.f);
    gemm_kernel<true, true, false><<<dim3(8, 64, 1), 256, 0, stream>>>(xb, wtk, bk, Kb, 8192, 1024, 1024, 0, 0, 0, 1.f);
    gemm_kernel<true, true, false><<<dim3(8, 64, 1), 256, 0, stream>>>(xb, wtv, bv, Vb, 8192, 1024, 1024, 0, 0, 0, 1.f);
    // V -> V^T per batch
    vt_kernel<<<dim3(32, 64, 4), 256, 0, stream>>>(Vb, Vt);
    // scores = (Q @ K^T) / 32, bf16, batched (M=N=2048, K=1024)
    gemm_kernel<false, true, true><<<dim3(16, 16, 4), 256, 0, stream>>>(
        Q, Kb, nullptr, Sc, 2048, 2048, 1024, 2048L * 1024, 2048L * 1024, 2048L * 2048, 0.03125f);
    // softmax rows, in place
    softmax_kernel<<<8192, 256, 0, stream>>>(Sc);
    // out = attn @ V, f32 out, batched (M=2048, N=1024, K=2048)
    gemm_kernel<false, false, false><<<dim3(8, 16, 4), 256, 0, stream>>>(
        Sc, Vt, nullptr, out, 2048, 1024, 2048, 2048L * 2048, 1024L * 2048, 2048L * 1024, 1.f);
}

// Round 2
// 217.429 us; speedup vs baseline: 2.7037x; 2.7037x over previous
//
#include <hip/hip_runtime.h>
#include <stdint.h>

// bf16 helpers ---------------------------------------------------------------
using short8  = __attribute__((ext_vector_type(8))) short;
using floatx4 = __attribute__((ext_vector_type(4))) float;

__device__ __forceinline__ unsigned short f2bf(float f) {
    unsigned u = __float_as_uint(f);
    u += 0x7fff + ((u >> 16) & 1);   // round-to-nearest-even
    return (unsigned short)(u >> 16);
}
__device__ __forceinline__ float bf2f(unsigned short h) {
    return __uint_as_float(((unsigned)h) << 16);
}

// async global->LDS, 16B per lane (global_load_lds_dwordx4)
__device__ __forceinline__ void gload_lds16(const void* g, void* l) {
    auto gp = reinterpret_cast<const __attribute__((address_space(1))) unsigned int*>(
        reinterpret_cast<uintptr_t>(g));
    auto lp = reinterpret_cast<__attribute__((address_space(3))) unsigned int*>(
        reinterpret_cast<uintptr_t>(l));
    __builtin_amdgcn_global_load_lds(gp, lp, 16, 0, 0);
}

// 1) convert x f32 -> bf16 ----------------------------------------------------
__global__ __launch_bounds__(256) void cvt_f32_bf16_kernel(
        const float* __restrict__ in, unsigned short* __restrict__ out) {
    long i = ((long)blockIdx.x * 256 + threadIdx.x) * 4;
    float4 v = *(const float4*)(in + i);
    ushort4 o;
    o.x = f2bf(v.x); o.y = f2bf(v.y); o.z = f2bf(v.z); o.w = f2bf(v.w);
    *(ushort4*)(out + i) = o;
}

// 2) W [1024][1024] f32 -> Wt bf16 [e][d] (transpose+convert), 3 weights ------
__global__ __launch_bounds__(256) void wt_kernel(
        const float* __restrict__ W0, const float* __restrict__ W1, const float* __restrict__ W2,
        unsigned short* __restrict__ O0, unsigned short* __restrict__ O1, unsigned short* __restrict__ O2) {
    const float* W = blockIdx.z == 0 ? W0 : blockIdx.z == 1 ? W1 : W2;
    unsigned short* O = blockIdx.z == 0 ? O0 : blockIdx.z == 1 ? O1 : O2;
    __shared__ float t[32][33];
    const int cx = threadIdx.x & 31, ry = threadIdx.x >> 5;
    const int d0 = blockIdx.x * 32, e0 = blockIdx.y * 32;
#pragma unroll
    for (int i = 0; i < 4; i++) t[ry + i * 8][cx] = W[(long)(d0 + ry + i * 8) * 1024 + e0 + cx];
    __syncthreads();
#pragma unroll
    for (int i = 0; i < 4; i++) O[(long)(e0 + ry + i * 8) * 1024 + d0 + cx] = f2bf(t[cx][ry + i * 8]);
}

// 3) V bf16 [4][2048][1024] -> Vt bf16 [4][1024][2048] ------------------------
__global__ __launch_bounds__(256) void vt_kernel(
        const unsigned short* __restrict__ V, unsigned short* __restrict__ Vt) {
    const int b = blockIdx.z;
    const unsigned short* v = V + (long)b * 2048 * 1024;
    unsigned short* o = Vt + (long)b * 1024 * 2048;
    __shared__ unsigned short t[32][33];
    const int cx = threadIdx.x & 31, ry = threadIdx.x >> 5;
    const int e0 = blockIdx.x * 32, t0 = blockIdx.y * 32;
#pragma unroll
    for (int i = 0; i < 4; i++) t[ry + i * 8][cx] = v[(long)(t0 + ry + i * 8) * 1024 + e0 + cx];
    __syncthreads();
#pragma unroll
    for (int i = 0; i < 4; i++) o[(long)(e0 + ry + i * 8) * 2048 + t0 + cx] = t[cx][ry + i * 8];
}

// 4) GEMM: C = A[M][K] @ Bt[N][K]^T, m97 structure: 128x128 tile, BK=64,
//    global_load_lds width-16 staging into LINEAR LDS, 4 waves (2x2),
//    each wave 64x64 = 4x4 frags of 16x16x32 bf16 MFMA.
// MODE 0: QKV fused — bias, split output into 3 buffers of row-stride 1024, bf16 out
// MODE 1: scores — *scale, bf16 out, batched
// MODE 2: PV — f32 out, batched
template <int MODE>
__global__ __launch_bounds__(256) void gemm_kernel(
        const unsigned short* __restrict__ A, const unsigned short* __restrict__ Bt,
        void* __restrict__ out0, void* __restrict__ out1, void* __restrict__ out2,
        const float* __restrict__ b0, const float* __restrict__ b1, const float* __restrict__ b2,
        int K, int N, long sAb, long sBb, long sCb, float scale) {
    __shared__ __align__(16) unsigned short sA[128][64];   // linear: required by global_load_lds
    __shared__ __align__(16) unsigned short sB[128][64];
    const int tid  = threadIdx.x;
    const int lane = tid & 63;
    const int wid  = tid >> 6;
    const int wm = wid >> 1, wn = wid & 1;
    const long m0 = (long)blockIdx.y * 128, n0 = (long)blockIdx.x * 128;
    A  += (long)blockIdx.z * sAb;
    Bt += (long)blockIdx.z * sBb;

    floatx4 acc[4][4] = {};

    // staging addresses: wave w stages rows [w*32, w*32+32) of each tile,
    // 4 chunks of 8 rows; lane l -> row +(l>>3), col (l&7)*8 (16B) == linear LDS order
    const unsigned short* Ap = A + (m0 + wid * 32 + (lane >> 3)) * (long)K + (lane & 7) * 8;
    const unsigned short* Bp = Bt + (n0 + wid * 32 + (lane >> 3)) * (long)K + (lane & 7) * 8;

    for (int k0 = 0; k0 < K; k0 += 64) {
        __syncthreads();                       // all waves done reading previous tile
#pragma unroll
        for (int i = 0; i < 4; i++) {
            gload_lds16(Ap + (long)(i * 8) * K + k0, &sA[wid * 32 + i * 8][0]);
            gload_lds16(Bp + (long)(i * 8) * K + k0, &sB[wid * 32 + i * 8][0]);
        }
        __syncthreads();                       // drains vmcnt(0): tile staged
#pragma unroll
        for (int ks = 0; ks < 2; ks++) {
            short8 af[4], bfr[4];
#pragma unroll
            for (int f = 0; f < 4; f++) {
                af[f]  = *(const short8*)&sA[wm * 64 + f * 16 + (lane & 15)][ks * 32 + (lane >> 4) * 8];
                bfr[f] = *(const short8*)&sB[wn * 64 + f * 16 + (lane & 15)][ks * 32 + (lane >> 4) * 8];
            }
#pragma unroll
            for (int fm = 0; fm < 4; fm++)
#pragma unroll
                for (int fn = 0; fn < 4; fn++)
                    acc[fm][fn] = __builtin_amdgcn_mfma_f32_16x16x32_bf16(af[fm], bfr[fn], acc[fm][fn], 0, 0, 0);
        }
    }

    // epilogue: C/D layout col=lane&15, row=(lane>>4)*4+j (HW-verified, round-1 pass)
    const int cr = (lane >> 4) * 4, cc = lane & 15;
    if (MODE == 0) {
        const int buf = (int)(n0 >> 10);       // 128 | 1024 -> whole block in one of q/k/v
        unsigned short* O = (unsigned short*)(buf == 0 ? out0 : buf == 1 ? out1 : out2);
        const float* bias = buf == 0 ? b0 : buf == 1 ? b1 : b2;
        const long nc0 = (n0 & 1023);
#pragma unroll
        for (int fn = 0; fn < 4; fn++) {
            const long col = nc0 + wn * 64 + fn * 16 + cc;
            const float bvv = bias[col];
#pragma unroll
            for (int fm = 0; fm < 4; fm++) {
                const long rbase = m0 + wm * 64 + fm * 16 + cr;
#pragma unroll
                for (int j = 0; j < 4; j++)
                    O[(rbase + j) * 1024 + col] = f2bf(acc[fm][fn][j] + bvv);
            }
        }
    } else {
#pragma unroll
        for (int fn = 0; fn < 4; fn++) {
            const long col = n0 + wn * 64 + fn * 16 + cc;
#pragma unroll
            for (int fm = 0; fm < 4; fm++) {
                const long rbase = m0 + wm * 64 + fm * 16 + cr;
#pragma unroll
                for (int j = 0; j < 4; j++) {
                    const long idx = (long)blockIdx.z * sCb + (rbase + j) * (long)N + col;
                    if (MODE == 1) ((unsigned short*)out0)[idx] = f2bf(acc[fm][fn][j] * scale);
                    else           ((float*)out0)[idx] = acc[fm][fn][j];
                }
            }
        }
    }
}

// 5) in-place row softmax over 2048 bf16 --------------------------------------
__global__ __launch_bounds__(256) void softmax_kernel(unsigned short* __restrict__ S) {
    unsigned short* p = S + (long)blockIdx.x * 2048;
    const int tid = threadIdx.x;
    union { int4 q; unsigned short u[8]; } in;
    in.q = *(const int4*)(p + tid * 8);
    float v[8];
#pragma unroll
    for (int i = 0; i < 8; i++) v[i] = bf2f(in.u[i]);
    float mx = v[0];
#pragma unroll
    for (int i = 1; i < 8; i++) mx = fmaxf(mx, v[i]);
#pragma unroll
    for (int off = 32; off; off >>= 1) mx = fmaxf(mx, __shfl_xor(mx, off));
    __shared__ float red[8];
    if ((tid & 63) == 0) red[tid >> 6] = mx;
    __syncthreads();
    mx = fmaxf(fmaxf(red[0], red[1]), fmaxf(red[2], red[3]));
    float s = 0.f;
#pragma unroll
    for (int i = 0; i < 8; i++) { v[i] = __expf(v[i] - mx); s += v[i]; }
#pragma unroll
    for (int off = 32; off; off >>= 1) s += __shfl_xor(s, off);
    if ((tid & 63) == 0) red[4 + (tid >> 6)] = s;
    __syncthreads();
    s = red[4] + red[5] + red[6] + red[7];
    const float inv = 1.f / s;
    union { int4 q; unsigned short u[8]; } out;
#pragma unroll
    for (int i = 0; i < 8; i++) out.u[i] = f2bf(v[i] * inv);
    *(int4*)(p + tid * 8) = out.q;
}

// -----------------------------------------------------------------------------
extern "C" void kernel_launch(void* const* d_in, const int* in_sizes, int n_in,
                              void* d_out, int out_size, void* d_ws, size_t ws_size,
                              hipStream_t stream) {
    const float* x  = (const float*)d_in[0];
    const float* Wq = (const float*)d_in[1];
    const float* bq = (const float*)d_in[2];
    const float* Wk = (const float*)d_in[3];
    const float* bk = (const float*)d_in[4];
    const float* Wv = (const float*)d_in[5];
    const float* bv = (const float*)d_in[6];
    float* out = (float*)d_out;

    char* ws = (char*)d_ws;
    const long MB = 1L << 20;
    unsigned short* xb  = (unsigned short*)(ws);            // 16 MB  x bf16 [8192][1024]
    unsigned short* wt  = (unsigned short*)(ws + 16 * MB);  // 6 MB   W{q,k,v}^T bf16 [3072][1024] contiguous
    unsigned short* Q   = (unsigned short*)(ws + 22 * MB);  // 16 MB  [4][2048][1024]
    unsigned short* Kb  = (unsigned short*)(ws + 38 * MB);  // 16 MB
    unsigned short* Vb  = (unsigned short*)(ws + 54 * MB);  // 16 MB
    unsigned short* Vt  = (unsigned short*)(ws + 70 * MB);  // 16 MB  [4][1024][2048]
    unsigned short* Sc  = (unsigned short*)(ws + 86 * MB);  // 32 MB  scores/attn [4][2048][2048]

    // x -> bf16
    cvt_f32_bf16_kernel<<<8192, 256, 0, stream>>>(x, xb);
    // W -> Wt bf16 (transposed, stacked: rows [0,1024)=Wq^T, [1024,2048)=Wk^T, [2048,3072)=Wv^T)
    wt_kernel<<<dim3(32, 32, 3), 256, 0, stream>>>(Wq, Wk, Wv, wt, wt + 1024 * 1024, wt + 2 * 1024 * 1024);
    // fused QKV: [8192][1024] @ [3072][1024]^T + bias -> Q|K|V (M=8192, Ncols=3072, K=1024)
    gemm_kernel<0><<<dim3(24, 64, 1), 256, 0, stream>>>(
        xb, wt, Q, Kb, Vb, bq, bk, bv, 1024, 3072, 0, 0, 0, 1.f);
    // V -> V^T per batch
    vt_kernel<<<dim3(32, 64, 4), 256, 0, stream>>>(Vb, Vt);
    // scores = (Q @ K^T) / 32, bf16, batched (M=N=2048, K=1024)
    gemm_kernel<1><<<dim3(16, 16, 4), 256, 0, stream>>>(
        Q, Kb, Sc, nullptr, nullptr, nullptr, nullptr, nullptr,
        1024, 2048, 2048L * 1024, 2048L * 1024, 2048L * 2048, 0.03125f);
    // softmax rows, in place
    softmax_kernel<<<8192, 256, 0, stream>>>(Sc);
    // out = attn @ V, f32 out, batched (M=2048, N=1024, K=2048)
    gemm_kernel<2><<<dim3(8, 16, 4), 256, 0, stream>>>(
        Sc, Vt, out, nullptr, nullptr, nullptr, nullptr, nullptr,
        2048, 1024, 2048L * 2048, 1024L * 2048, 2048L * 1024, 1.f);
}

// Round 3
// 198.596 us; speedup vs baseline: 2.9601x; 1.0948x over previous
//
#include <hip/hip_runtime.h>
#include <stdint.h>
#include <type_traits>

typedef unsigned short u16;
using short8  = __attribute__((ext_vector_type(8))) short;
using floatx4 = __attribute__((ext_vector_type(4))) float;

#define IC(n) (std::integral_constant<int, (n)>())

__device__ __forceinline__ u16 f2bf(float f) {
    unsigned u = __float_as_uint(f);
    u += 0x7fff + ((u >> 16) & 1);   // round-to-nearest-even
    return (u16)(u >> 16);
}
__device__ __forceinline__ float bf2f(u16 h) {
    return __uint_as_float(((unsigned)h) << 16);
}

// async global->LDS, 16B per lane (global_load_lds_dwordx4)
__device__ __forceinline__ void gload_lds16(const void* g, void* l) {
    auto gp = reinterpret_cast<const __attribute__((address_space(1))) unsigned int*>(
        reinterpret_cast<uintptr_t>(g));
    auto lp = reinterpret_cast<__attribute__((address_space(3))) unsigned int*>(
        reinterpret_cast<uintptr_t>(l));
    __builtin_amdgcn_global_load_lds(gp, lp, 16, 0, 0);
}

// 1) convert x f32 -> bf16 ----------------------------------------------------
__global__ __launch_bounds__(256) void cvt_f32_bf16_kernel(
        const float* __restrict__ in, u16* __restrict__ out) {
    long i = ((long)blockIdx.x * 256 + threadIdx.x) * 4;
    float4 v = *(const float4*)(in + i);
    ushort4 o;
    o.x = f2bf(v.x); o.y = f2bf(v.y); o.z = f2bf(v.z); o.w = f2bf(v.w);
    *(ushort4*)(out + i) = o;
}

// 2) W [1024][1024] f32 -> Wt bf16 [e][d] (transpose+convert), 3 weights ------
__global__ __launch_bounds__(256) void wt_kernel(
        const float* __restrict__ W0, const float* __restrict__ W1, const float* __restrict__ W2,
        u16* __restrict__ O0, u16* __restrict__ O1, u16* __restrict__ O2) {
    const float* W = blockIdx.z == 0 ? W0 : blockIdx.z == 1 ? W1 : W2;
    u16* O = blockIdx.z == 0 ? O0 : blockIdx.z == 1 ? O1 : O2;
    __shared__ float t[32][33];
    const int cx = threadIdx.x & 31, ry = threadIdx.x >> 5;
    const int d0 = blockIdx.x * 32, e0 = blockIdx.y * 32;
#pragma unroll
    for (int i = 0; i < 4; i++) t[ry + i * 8][cx] = W[(long)(d0 + ry + i * 8) * 1024 + e0 + cx];
    __syncthreads();
#pragma unroll
    for (int i = 0; i < 4; i++) O[(long)(e0 + ry + i * 8) * 1024 + d0 + cx] = f2bf(t[cx][ry + i * 8]);
}

// 3) V bf16 [4][2048][1024] -> Vt bf16 [4][1024][2048] ------------------------
__global__ __launch_bounds__(256) void vt_kernel(
        const u16* __restrict__ V, u16* __restrict__ Vt) {
    const int b = blockIdx.z;
    const u16* v = V + (long)b * 2048 * 1024;
    u16* o = Vt + (long)b * 1024 * 2048;
    __shared__ u16 t[32][33];
    const int cx = threadIdx.x & 31, ry = threadIdx.x >> 5;
    const int e0 = blockIdx.x * 32, t0 = blockIdx.y * 32;
#pragma unroll
    for (int i = 0; i < 4; i++) t[ry + i * 8][cx] = v[(long)(t0 + ry + i * 8) * 1024 + e0 + cx];
    __syncthreads();
#pragma unroll
    for (int i = 0; i < 4; i++) o[(long)(e0 + ry + i * 8) * 2048 + t0 + cx] = t[cx][ry + i * 8];
}

// 4) 256x256 8-phase GEMM (m201 port): C = A[M][K] @ Bt[N][K]^T ---------------
// 8 waves (2M x 4N), wave tile 128x64, BK=64, 2 LDS dbufs (128 KiB total),
// XOR-swizzled LDS (linear gload_lds dest + inverse-swizzled global source),
// counted vmcnt(6) at phases 4/8 only, setprio(1) around MFMA clusters.
// MODE 0: QKV fused (bias, 3 split bf16 outputs, row stride 1024)
// MODE 1: scores (*scale, bf16 out, batched)
// MODE 2: PV (f32 out, batched)
template <int MODE>
__global__ __launch_bounds__(512) void gemm8_kernel(
        const u16* __restrict__ A, const u16* __restrict__ Bt,
        void* __restrict__ out0, void* __restrict__ out1, void* __restrict__ out2,
        const float* __restrict__ b0, const float* __restrict__ b1, const float* __restrict__ b2,
        int K, int N, long sAb, long sBb, long sCb, float scale)
{
    extern __shared__ u16 lds[];   // [dbuf:2][ A(2 halves x 128 x 64) | B(2 halves x 128 x 64) ]
    const int tid = threadIdx.x, lane = tid & 63, wid = tid >> 6;
    const int wm = wid >> 2, wn = wid & 3;
    const int l15 = lane & 15, hib = (lane >> 4) * 16;   // byte col offset of frag

    // XCD-aware bijective swizzle (all our grids have nwg % 8 == 0)
    const int nbx = gridDim.x;
    const int nwg = nbx * gridDim.y;
    int lin = blockIdx.y * nbx + blockIdx.x;
    lin = (lin & 7) * (nwg >> 3) + (lin >> 3);
    const long m0 = (long)(lin / nbx) * 256;
    const long n0 = (long)(lin % nbx) * 256;

    const u16* Ab = A + (long)blockIdx.z * sAb;
    const u16* Bb = Bt + (long)blockIdx.z * sBb;
    const long ldk = K;
    const int NT = K >> 6;          // K-tiles of 64

    // ---- staging: one "unit" = 16KB, 2 x gload_lds16 per thread ------------
    // A unit S: rows {half*128 + S*64 + [0,64)} (the mh=S quadrant rows, both halves)
    auto stA = [&](int dbuf, int S, int kt) {
#pragma unroll
        for (int i = 0; i < 2; ++i) {
            const int rl = tid >> 3;                    // 0..63
            const int R  = S * 64 + rl;                 // row within half
            const int cb = (tid & 7) * 16;
            const int scb = cb ^ ((R & 7) << 4);        // inverse swizzle on SOURCE
            const u16* src = Ab + (m0 + i * 128 + R) * ldk + (long)kt * 64 + (scb >> 1);
            u16* dst = lds + dbuf * 32768 + i * 8192 + S * 4096 + wid * 512;
            gload_lds16(src, dst);
        }
    };
    // B unit NHs: rows {half*128 + rb + NHs*32 + [0,32) : rb in {0,64}} (nh=NHs rows)
    auto stB = [&](int dbuf, int NHs, int kt) {
#pragma unroll
        for (int i = 0; i < 2; ++i) {
            const int c = i * 2 + (wid >> 2);           // chunk 0..3 (wave-uniform)
            const int h = c >> 1, rb = (c & 1) * 64;
            const int w = (wid & 3) * 64 + lane;        // 0..255 within chunk
            const int r32 = w >> 3;                     // 0..31
            const int R = rb + NHs * 32 + r32;          // row within half
            const int cb = (w & 7) * 16;
            const int scb = cb ^ ((R & 7) << 4);
            const u16* src = Bb + (n0 + h * 128 + R) * ldk + (long)kt * 64 + (scb >> 1);
            u16* dst = lds + dbuf * 32768 + 16384 + h * 8192 + (rb + NHs * 32) * 64 + (wid & 3) * 512;
            gload_lds16(src, dst);
        }
    };

    floatx4 acc[8][4] = {};
    short8 afr[4][2], bfr[2][2];

    auto LA = [&](int dbuf, auto MHc) {
        constexpr int MH = decltype(MHc)::value;
        const char* reg = (const char*)(lds + dbuf * 32768 + wm * 8192);
#pragma unroll
        for (int fm = 0; fm < 4; ++fm)
#pragma unroll
            for (int ks = 0; ks < 2; ++ks) {
                const int r = MH * 64 + fm * 16 + l15;
                const int cb = ks * 64 + hib;
                afr[fm][ks] = *(const short8*)(reg + r * 128 + (cb ^ ((r & 7) << 4)));
            }
    };
    auto LB = [&](int dbuf, auto NHc) {
        constexpr int NH = decltype(NHc)::value;
        const char* reg = (const char*)(lds + dbuf * 32768 + 16384 + (wn >> 1) * 8192);
#pragma unroll
        for (int fn = 0; fn < 2; ++fn)
#pragma unroll
            for (int ks = 0; ks < 2; ++ks) {
                const int r = (wn & 1) * 64 + NH * 32 + fn * 16 + l15;
                const int cb = ks * 64 + hib;
                bfr[fn][ks] = *(const short8*)(reg + r * 128 + (cb ^ ((r & 7) << 4)));
            }
    };
    auto MM = [&](auto MHc, auto NHc) {
        constexpr int MH = decltype(MHc)::value;
        constexpr int NH = decltype(NHc)::value;
        __builtin_amdgcn_s_setprio(1);
#pragma unroll
        for (int fm = 0; fm < 4; ++fm)
#pragma unroll
            for (int fn = 0; fn < 2; ++fn)
#pragma unroll
                for (int ks = 0; ks < 2; ++ks)
                    acc[MH * 4 + fm][NH * 2 + fn] = __builtin_amdgcn_mfma_f32_16x16x32_bf16(
                        afr[fm][ks], bfr[fn][ks], acc[MH * 4 + fm][NH * 2 + fn], 0, 0, 0);
        __builtin_amdgcn_s_setprio(0);
    };

#define BAR()   __builtin_amdgcn_s_barrier()
#define WAIT0() asm volatile("s_waitcnt lgkmcnt(0)" ::: "memory")

    // ---- prologue: stage kt0 fully + kt1 {A0, B1, A1}; 14 loads, keep 6 in flight
    stA(0, 0, 0); stA(0, 1, 0); stB(0, 0, 0); stB(0, 1, 0);
    stA(1, 0, 1); stB(1, 1, 1); stA(1, 1, 1);
    asm volatile("s_waitcnt vmcnt(6)");
    BAR();

    // ---- main loop: one iteration = 2 K-tiles = 8 phases --------------------
    auto pair = [&](auto LASTC, int kt0) {
        constexpr bool L = decltype(LASTC)::value;
        // ph1: (mh0,nh0) of kt0[dbuf0]; stage B0(kt0+1)->dbuf1 (dead since prev ph8)
        LA(0, IC(0)); LB(0, IC(0));
        stB(1, 0, kt0 + 1);
        asm volatile("s_waitcnt lgkmcnt(8)");
        BAR(); WAIT0(); MM(IC(0), IC(0)); BAR();
        // ph2: (mh0,nh1); stage A0(kt0+2)->dbuf0 (A0 dead after ph1)
        LB(0, IC(1));
        if (!L) stA(0, 0, kt0 + 2);
        BAR(); WAIT0(); MM(IC(0), IC(1)); BAR();
        // ph3: (mh1,nh1); stage B1(kt0+2) (B1 dead after ph2)
        LA(0, IC(1));
        if (!L) stB(0, 1, kt0 + 2);
        BAR(); WAIT0(); MM(IC(1), IC(1)); BAR();
        // ph4: (mh1,nh0); stage A1(kt0+2) (A1 dead after ph3); vmcnt gate for dbuf1
        LB(0, IC(0));
        if (!L) stA(0, 1, kt0 + 2);
        BAR(); WAIT0(); MM(IC(1), IC(0));
        if (L) asm volatile("s_waitcnt vmcnt(0)");
        else   asm volatile("s_waitcnt vmcnt(6)");
        BAR();
        // ph5: (mh0,nh0) of kt0+1[dbuf1]; stage B0(kt0+2) (B0 dead after ph4)
        LA(1, IC(0)); LB(1, IC(0));
        if (!L) stB(0, 0, kt0 + 2);
        asm volatile("s_waitcnt lgkmcnt(8)");
        BAR(); WAIT0(); MM(IC(0), IC(0)); BAR();
        // ph6: (mh0,nh1); stage A0(kt0+3)->dbuf1 (dead after ph5)
        LB(1, IC(1));
        if (!L) stA(1, 0, kt0 + 3);
        BAR(); WAIT0(); MM(IC(0), IC(1)); BAR();
        // ph7: (mh1,nh1); stage B1(kt0+3) (dead after ph6)
        LA(1, IC(1));
        if (!L) stB(1, 1, kt0 + 3);
        BAR(); WAIT0(); MM(IC(1), IC(1)); BAR();
        // ph8: (mh1,nh0); stage A1(kt0+3) (dead after ph7); vmcnt gate for dbuf0
        LB(1, IC(0));
        if (!L) stA(1, 1, kt0 + 3);
        BAR(); WAIT0(); MM(IC(1), IC(0));
        if (L) asm volatile("s_waitcnt vmcnt(0)");
        else   asm volatile("s_waitcnt vmcnt(6)");
        BAR();
    };

    const int NITER = NT >> 1;
    int it = 0;
    for (; it < NITER - 1; ++it) pair(std::false_type{}, 2 * it);
    pair(std::true_type{}, 2 * it);

#undef BAR
#undef WAIT0

    // ---- epilogue: C/D layout col=lane&15, row=(lane>>4)*4+j (HW-verified) --
    const int cr = (lane >> 4) * 4, cc = l15;
    if (MODE == 0) {
        const int sel = (int)(n0 >> 10);   // 256 | 1024: block entirely in one of q/k/v
        u16* O = (u16*)(sel == 0 ? out0 : sel == 1 ? out1 : out2);
        const float* bias = sel == 0 ? b0 : sel == 1 ? b1 : b2;
        const long nc0 = n0 & 1023;
#pragma unroll
        for (int an = 0; an < 4; ++an) {
            const long col = nc0 + wn * 64 + an * 16 + cc;
            const float bvv = bias[col];
#pragma unroll
            for (int am = 0; am < 8; ++am) {
                const long row = m0 + wm * 128 + am * 16 + cr;
#pragma unroll
                for (int j = 0; j < 4; ++j)
                    O[(row + j) * 1024 + col] = f2bf(acc[am][an][j] + bvv);
            }
        }
    } else {
#pragma unroll
        for (int an = 0; an < 4; ++an) {
            const long col = n0 + wn * 64 + an * 16 + cc;
#pragma unroll
            for (int am = 0; am < 8; ++am) {
                const long row = m0 + wm * 128 + am * 16 + cr;
#pragma unroll
                for (int j = 0; j < 4; ++j) {
                    const long idx = (long)blockIdx.z * sCb + (row + j) * (long)N + col;
                    if (MODE == 1) ((u16*)out0)[idx] = f2bf(acc[am][an][j] * scale);
                    else           ((float*)out0)[idx] = acc[am][an][j];
                }
            }
        }
    }
}

// 5) in-place row softmax over 2048 bf16 --------------------------------------
__global__ __launch_bounds__(256) void softmax_kernel(u16* __restrict__ S) {
    u16* p = S + (long)blockIdx.x * 2048;
    const int tid = threadIdx.x;
    union { int4 q; u16 u[8]; } in;
    in.q = *(const int4*)(p + tid * 8);
    float v[8];
#pragma unroll
    for (int i = 0; i < 8; i++) v[i] = bf2f(in.u[i]);
    float mx = v[0];
#pragma unroll
    for (int i = 1; i < 8; i++) mx = fmaxf(mx, v[i]);
#pragma unroll
    for (int off = 32; off; off >>= 1) mx = fmaxf(mx, __shfl_xor(mx, off));
    __shared__ float red[8];
    if ((tid & 63) == 0) red[tid >> 6] = mx;
    __syncthreads();
    mx = fmaxf(fmaxf(red[0], red[1]), fmaxf(red[2], red[3]));
    float s = 0.f;
#pragma unroll
    for (int i = 0; i < 8; i++) { v[i] = __expf(v[i] - mx); s += v[i]; }
#pragma unroll
    for (int off = 32; off; off >>= 1) s += __shfl_xor(s, off);
    if ((tid & 63) == 0) red[4 + (tid >> 6)] = s;
    __syncthreads();
    s = red[4] + red[5] + red[6] + red[7];
    const float inv = 1.f / s;
    union { int4 q; u16 u[8]; } out;
#pragma unroll
    for (int i = 0; i < 8; i++) out.u[i] = f2bf(v[i] * inv);
    *(int4*)(p + tid * 8) = out.q;
}

// -----------------------------------------------------------------------------
extern "C" void kernel_launch(void* const* d_in, const int* in_sizes, int n_in,
                              void* d_out, int out_size, void* d_ws, size_t ws_size,
                              hipStream_t stream) {
    const float* x  = (const float*)d_in[0];
    const float* Wq = (const float*)d_in[1];
    const float* bq = (const float*)d_in[2];
    const float* Wk = (const float*)d_in[3];
    const float* bk = (const float*)d_in[4];
    const float* Wv = (const float*)d_in[5];
    const float* bv = (const float*)d_in[6];
    float* out = (float*)d_out;

    char* ws = (char*)d_ws;
    const long MB = 1L << 20;
    u16* xb = (u16*)(ws);            // 16 MB  x bf16 [8192][1024]
    u16* wt = (u16*)(ws + 16 * MB);  // 6 MB   W{q,k,v}^T bf16 [3072][1024] stacked
    u16* Q  = (u16*)(ws + 22 * MB);  // 16 MB  [4][2048][1024]
    u16* Kb = (u16*)(ws + 38 * MB);  // 16 MB
    u16* Vb = (u16*)(ws + 54 * MB);  // 16 MB
    u16* Vt = (u16*)(ws + 70 * MB);  // 16 MB  [4][1024][2048]
    u16* Sc = (u16*)(ws + 86 * MB);  // 32 MB  scores/attn [4][2048][2048]

    // allow 128 KiB dynamic LDS (idempotent; host-side, capture-safe)
    (void)hipFuncSetAttribute((const void*)gemm8_kernel<0>, hipFuncAttributeMaxDynamicSharedMemorySize, 131072);
    (void)hipFuncSetAttribute((const void*)gemm8_kernel<1>, hipFuncAttributeMaxDynamicSharedMemorySize, 131072);
    (void)hipFuncSetAttribute((const void*)gemm8_kernel<2>, hipFuncAttributeMaxDynamicSharedMemorySize, 131072);

    // x -> bf16
    cvt_f32_bf16_kernel<<<8192, 256, 0, stream>>>(x, xb);
    // W -> Wt bf16 (transposed, stacked)
    wt_kernel<<<dim3(32, 32, 3), 256, 0, stream>>>(Wq, Wk, Wv, wt, wt + 1024 * 1024, wt + 2 * 1024 * 1024);
    // fused QKV: [8192][1024] @ [3072][1024]^T + bias (M=8192, N=3072, K=1024)
    gemm8_kernel<0><<<dim3(12, 32, 1), 512, 131072, stream>>>(
        xb, wt, Q, Kb, Vb, bq, bk, bv, 1024, 3072, 0, 0, 0, 1.f);
    // V -> V^T per batch
    vt_kernel<<<dim3(32, 64, 4), 256, 0, stream>>>(Vb, Vt);
    // scores = (Q @ K^T) / 32, bf16, batched (M=N=2048, K=1024)
    gemm8_kernel<1><<<dim3(8, 8, 4), 512, 131072, stream>>>(
        Q, Kb, Sc, nullptr, nullptr, nullptr, nullptr, nullptr,
        1024, 2048, 2048L * 1024, 2048L * 1024, 2048L * 2048, 0.03125f);
    // softmax rows, in place
    softmax_kernel<<<8192, 256, 0, stream>>>(Sc);
    // out = attn @ V, f32 out, batched (M=2048, N=1024, K=2048)
    gemm8_kernel<2><<<dim3(4, 8, 4), 512, 131072, stream>>>(
        Sc, Vt, out, nullptr, nullptr, nullptr, nullptr, nullptr,
        2048, 1024, 2048L * 2048, 1024L * 2048, 2048L * 1024, 1.f);
}